// Round 5
// baseline (1153.056 us; speedup 1.0000x reference)
//
#include <hip/hip_runtime.h>
#include <math.h>

#define TT 512
#define BB 512
#define CC 32
#define CIN 33
#define HH 128
#define EPSF 1e-12f
#define CH 16              // timesteps per x-chunk staged in LDS
#define NCH (TT / CH)

typedef _Float16 half8 __attribute__((ext_vector_type(8)));
typedef _Float16 half4 __attribute__((ext_vector_type(4)));
typedef float f32x4 __attribute__((ext_vector_type(4)));

#define MFMA16H(a, b, c) __builtin_amdgcn_mfma_f32_16x16x32_f16(a, b, c, 0, 0, 0)

__device__ __forceinline__ float fsig(float x) { return 1.f / (1.f + __expf(-x)); }
__device__ __forceinline__ float ftanh(float x) { return 1.f - 2.f / (1.f + __expf(2.f * x)); }

// ---------------------------------------------------------------------------
// Kernel 1: s[t] = mean_c std_b(x[:,t,c], ddof=1)   -> ws[0..511]
// ---------------------------------------------------------------------------
__global__ void std_kernel(const float* __restrict__ x, float* __restrict__ ws) {
    const int t = blockIdx.x;
    const int c = threadIdx.x & 31;
    const int sl = threadIdx.x >> 5;
    float sum = 0.f, sq = 0.f;
    for (int k = 0; k < 64; ++k) {
        const int b = sl * 64 + k;
        float v = x[((size_t)b * TT + t) * CC + c];
        sum += v;
        sq  = fmaf(v, v, sq);
    }
    __shared__ float rs[8][32];
    __shared__ float rq[8][32];
    rs[sl][c] = sum; rq[sl][c] = sq;
    __syncthreads();
    if (threadIdx.x < 32) {
        float S = 0.f, Q = 0.f;
        for (int i = 0; i < 8; ++i) { S += rs[i][threadIdx.x]; Q += rq[i][threadIdx.x]; }
        float mean = S / 512.0f;
        float var  = (Q - 512.0f * mean * mean) / 511.0f;
        rs[0][threadIdx.x] = sqrtf(fmaxf(var, 0.f));
    }
    __syncthreads();
    if (threadIdx.x == 0) {
        float m = 0.f;
        for (int i = 0; i < 32; ++i) m += rs[0][i];
        ws[t] = m / 32.0f;
    }
}

// ---------------------------------------------------------------------------
// Kernel 2: sigmas -> ws[512]=sig_ih, ws[513]=sig_hh, ws[514]=sig_fc
// ---------------------------------------------------------------------------
__global__ void sigma_kernel(const float* __restrict__ w_ih, const float* __restrict__ u_ih,
                             const float* __restrict__ w_hh, const float* __restrict__ u_hh,
                             const float* __restrict__ fc_w, const float* __restrict__ u_fc,
                             float* __restrict__ ws) {
    const int tid = threadIdx.x;
    __shared__ float red[512];
    __shared__ float vv[128];

    {   // sigma_hh
        const int c = tid & 127, q = tid >> 7;
        float part = 0.f;
        for (int g = q * 128; g < q * 128 + 128; ++g)
            part = fmaf(w_hh[g * HH + c], u_hh[g], part);
        red[tid] = part;
        __syncthreads();
        if (tid < 128) vv[tid] = red[tid] + red[tid + 128] + red[tid + 256] + red[tid + 384];
        __syncthreads();
        red[tid] = (tid < 128) ? vv[tid] * vv[tid] : 0.f;
        __syncthreads();
        for (int s = 64; s >= 1; s >>= 1) { if (tid < s) red[tid] += red[tid + s]; __syncthreads(); }
        const float nv = sqrtf(red[0]);
        __syncthreads();
        if (tid < 128) vv[tid] = vv[tid] / (nv + EPSF);
        __syncthreads();
        float wv = 0.f;
        for (int c2 = 0; c2 < 128; ++c2) wv = fmaf(w_hh[tid * HH + c2], vv[c2], wv);
        red[tid] = wv * wv;
        __syncthreads();
        for (int s = 256; s >= 1; s >>= 1) { if (tid < s) red[tid] += red[tid + s]; __syncthreads(); }
        if (tid == 0) { float ns2 = red[0]; ws[513] = ns2 / (sqrtf(ns2) + EPSF); }
        __syncthreads();
    }
    {   // sigma_ih
        float part = 0.f;
        if (tid < CIN) {
            for (int g = 0; g < 512; ++g) part = fmaf(w_ih[g * CIN + tid], u_ih[g], part);
            red[tid] = part;
        }
        __syncthreads();
        if (tid == 0) {
            float n2 = 0.f;
            for (int i = 0; i < CIN; ++i) n2 += red[i] * red[i];
            red[400] = sqrtf(n2);
        }
        __syncthreads();
        const float nv = red[400];
        if (tid < CIN) vv[tid] = red[tid] / (nv + EPSF);
        __syncthreads();
        float wv = 0.f;
        for (int c2 = 0; c2 < CIN; ++c2) wv = fmaf(w_ih[tid * CIN + c2], vv[c2], wv);
        red[tid] = wv * wv;
        __syncthreads();
        for (int s = 256; s >= 1; s >>= 1) { if (tid < s) red[tid] += red[tid + s]; __syncthreads(); }
        if (tid == 0) { float ns2 = red[0]; ws[512] = ns2 / (sqrtf(ns2) + EPSF); }
        __syncthreads();
    }
    {   // sigma_fc
        red[tid] = (tid < 128) ? fc_w[tid] * fc_w[tid] : 0.f;
        __syncthreads();
        for (int s = 64; s >= 1; s >>= 1) { if (tid < s) red[tid] += red[tid + s]; __syncthreads(); }
        if (tid == 0) {
            float nw2 = red[0];
            float u0  = u_fc[0];
            float nv  = fabsf(u0) * sqrtf(nw2);
            float wv  = u0 * nw2 / (nv + EPSF);
            ws[514]   = wv * wv / (fabsf(wv) + EPSF);
        }
    }
}

// ---------------------------------------------------------------------------
// Kernel 3: fp16 MFMA LSTM, chunked-x edition.
// Round-5 fix: __syncthreads drains vmcnt(0) every step, so ANY per-step
// global load costs a full memory latency per step. x and s[t] are now staged
// into LDS in 16-step chunks (one vmcnt drain per 16 steps). Attention uses
// fixed-shift softmax (|logit| <= ~3) -> no running-max serial chain.
// ---------------------------------------------------------------------------
__global__ __attribute__((amdgpu_flat_work_group_size(512, 512), amdgpu_waves_per_eu(2, 2)))
void lstm_mfma(
    const float* __restrict__ x,
    const float* __restrict__ w_ih, const float* __restrict__ w_hh,
    const float* __restrict__ b_ih, const float* __restrict__ b_hh,
    const float* __restrict__ attn_w, const float* __restrict__ attn_b,
    const float* __restrict__ fc_w, const float* __restrict__ fc_b,
    const float* __restrict__ ws,
    float* __restrict__ out)
{
    const int tid = threadIdx.x;
    const int w   = tid >> 6;          // wave 0..7
    const int l   = tid & 63;          // lane
    const int m   = l & 15;            // A-row / B-col index
    const int q   = l >> 4;            // quad 0..3
    const int b0  = blockIdx.x * 16;
    const int jcol = 16 * w + m;       // this lane's h column

    const float rih = 1.f / ws[512];
    const float rhh = 1.f / ws[513];
    const float rfc = 1.f / ws[514];
    const float attb = attn_b[0];

    __shared__ __align__(16) _Float16 hs[2][16][136];        // h planes (fp16)
    __shared__ __align__(16) _Float16 xs[2][CH][16][40];     // x chunks (fp16)
    __shared__ float ss[2][CH];                              // s[t] chunk
    __shared__ __align__(16) float bcast[2][16];             // beta per row
    __shared__ float Sf[16];

    // ---- stationary fp16 weights: B-frags Bf[p][kt] ----
    half8 Bf[4][5];
    float biasg[4], w32g[4];
#pragma unroll
    for (int p = 0; p < 4; ++p) {
        const int g = 16 * w + 128 * p + m;
#pragma unroll
        for (int kt = 0; kt < 4; ++kt) {
            const float* src = w_hh + (size_t)g * HH + kt * 32 + q * 8;
#pragma unroll
            for (int i = 0; i < 8; ++i) Bf[p][kt][i] = (_Float16)(src[i] * rhh);
        }
        {
            const float* src = w_ih + (size_t)g * CIN + q * 8;
#pragma unroll
            for (int i = 0; i < 8; ++i) Bf[p][4][i] = (_Float16)(src[i] * rih);
        }
        w32g[p]  = w_ih[(size_t)g * CIN + 32] * rih;
        biasg[p] = b_ih[g] + b_hh[g];
    }
#pragma unroll
    for (int p = 0; p < 4; ++p) {
#pragma unroll
        for (int kt = 0; kt < 5; ++kt) asm volatile("" : "+v"(Bf[p][kt]));
        asm volatile("" : "+v"(biasg[p]), "+v"(w32g[p]));
    }
    const float fcwj = fc_w[jcol] * rfc;

    // logit-phase role: row rrow (2 rows/wave), K-chunk kc
    const int rrow = 2 * w + (l >> 5);
    const int kc   = l & 31;
    float aw[4];
#pragma unroll
    for (int i = 0; i < 4; ++i) aw[i] = attn_w[kc * 4 + i];

    // chunk-stage decomposition for this thread: j = tid + 512*n
    // j -> c4 = j&7, k = (j>>3)&15, r = j>>7   (coalesced: 2 KB contiguous per r)

    // prologue: zero h_{-1} (buffer 1), stage chunk 0 + ss[0]
    for (int i = tid; i < 16 * 136; i += 512) (&hs[1][0][0])[i] = (_Float16)0.f;
#pragma unroll
    for (int n = 0; n < 4; ++n) {
        const int j = tid + 512 * n;
        const int c4 = j & 7, k = (j >> 3) & 15, r = j >> 7;
        float4 xv = *reinterpret_cast<const float4*>(x + ((size_t)(b0 + r) * TT + k) * CC + c4 * 4);
        half4 hv = {(_Float16)xv.x, (_Float16)xv.y, (_Float16)xv.z, (_Float16)xv.w};
        *(half4*)&xs[0][k][r][c4 * 4] = hv;
    }
    if (tid < CH) ss[0][tid] = ws[tid];

    float c_st[4] = {0.f, 0.f, 0.f, 0.f};
    float P[4]    = {0.f, 0.f, 0.f, 0.f};
    float hprev[4] = {0.f, 0.f, 0.f, 0.f};   // h_{t-1}
    float hpp[4]   = {0.f, 0.f, 0.f, 0.f};   // h_{t-2}
    float Sreg = 0.f;
    __syncthreads();

    for (int tc = 0; tc < NCH; ++tc) {
        const int cb = tc & 1;

        // stage next chunk (drained by first in-chunk barrier: 1 latency / 16 steps)
        if (tc + 1 < NCH) {
            const int nb  = (tc + 1) & 1;
            const int t0n = (tc + 1) * CH;
#pragma unroll
            for (int n = 0; n < 4; ++n) {
                const int j = tid + 512 * n;
                const int c4 = j & 7, k = (j >> 3) & 15, r = j >> 7;
                float4 xv = *reinterpret_cast<const float4*>(
                    x + ((size_t)(b0 + r) * TT + (t0n + k)) * CC + c4 * 4);
                half4 hv = {(_Float16)xv.x, (_Float16)xv.y, (_Float16)xv.z, (_Float16)xv.w};
                *(half4*)&xs[nb][k][r][c4 * 4] = hv;
            }
            if (tid < CH) ss[nb][tid] = ws[t0n + tid];
        }

        for (int k = 0; k < CH; ++k) {
            const int t  = tc * CH + k;
            const int hb = (t + 1) & 1;    // buffer holding h_{t-1}

            // ---- A-frag LDS reads issued first ----
            half8 ah0 = *(const half8*)&hs[hb][m][0 * 32 + q * 8];
            half8 ah1 = *(const half8*)&hs[hb][m][1 * 32 + q * 8];
            half8 ah2 = *(const half8*)&hs[hb][m][2 * 32 + q * 8];
            half8 ah3 = *(const half8*)&hs[hb][m][3 * 32 + q * 8];
            half8 ah4 = *(const half8*)&xs[cb][k][m][q * 8];
            const float s_t = ss[cb][k];

            // ---- logit for h_{t-1} (fixed-shift softmax: |logit| <= ~3) ----
            if (t > 0) {
                half4 hh = *(const half4*)&hs[hb][rrow][kc * 4];
                float acc = 0.f;
#pragma unroll
                for (int i = 0; i < 4; ++i) acc = fmaf(aw[i], (float)hh[i], acc);
#pragma unroll
                for (int off = 1; off < 32; off <<= 1) acc += __shfl_xor(acc, off, 64);
                float beta = __expf(acc + attb);
                Sreg += beta;
                if (kc == 0) bcast[t & 1][rrow] = beta;
            }

            // ---- P update for h_{t-2} (beta written at step t-1) ----
            if (t >= 2) {
                f32x4 bb = *(const f32x4*)&bcast[(t - 1) & 1][q * 4];
#pragma unroll
                for (int i = 0; i < 4; ++i) P[i] = fmaf(bb[i], hpp[i], P[i]);
            }

            // ---- gates: C init + 20 MFMA ----
            f32x4 acc0, acc1, acc2, acc3;
            {
                float c0 = fmaf(w32g[0], s_t, biasg[0]);
                float c1 = fmaf(w32g[1], s_t, biasg[1]);
                float c2 = fmaf(w32g[2], s_t, biasg[2]);
                float c3 = fmaf(w32g[3], s_t, biasg[3]);
                acc0 = (f32x4){c0, c0, c0, c0};
                acc1 = (f32x4){c1, c1, c1, c1};
                acc2 = (f32x4){c2, c2, c2, c2};
                acc3 = (f32x4){c3, c3, c3, c3};
            }
            acc0 = MFMA16H(ah0, Bf[0][0], acc0);
            acc1 = MFMA16H(ah0, Bf[1][0], acc1);
            acc2 = MFMA16H(ah0, Bf[2][0], acc2);
            acc3 = MFMA16H(ah0, Bf[3][0], acc3);
            acc0 = MFMA16H(ah1, Bf[0][1], acc0);
            acc1 = MFMA16H(ah1, Bf[1][1], acc1);
            acc2 = MFMA16H(ah1, Bf[2][1], acc2);
            acc3 = MFMA16H(ah1, Bf[3][1], acc3);
            acc0 = MFMA16H(ah2, Bf[0][2], acc0);
            acc1 = MFMA16H(ah2, Bf[1][2], acc1);
            acc2 = MFMA16H(ah2, Bf[2][2], acc2);
            acc3 = MFMA16H(ah2, Bf[3][2], acc3);
            acc0 = MFMA16H(ah3, Bf[0][3], acc0);
            acc1 = MFMA16H(ah3, Bf[1][3], acc1);
            acc2 = MFMA16H(ah3, Bf[2][3], acc2);
            acc3 = MFMA16H(ah3, Bf[3][3], acc3);
            acc0 = MFMA16H(ah4, Bf[0][4], acc0);
            acc1 = MFMA16H(ah4, Bf[1][4], acc1);
            acc2 = MFMA16H(ah4, Bf[2][4], acc2);
            acc3 = MFMA16H(ah4, Bf[3][4], acc3);

            // ---- activations + state update (rows q*4+i, column jcol) ----
#pragma unroll
            for (int i = 0; i < 4; ++i) {
                float ig = fsig(acc0[i]);
                float fg = fsig(acc1[i]);
                float gg = ftanh(acc2[i]);
                float og = fsig(acc3[i]);
                c_st[i] = fmaf(fg, c_st[i], ig * gg);
                float hv = og * ftanh(c_st[i]);
                hpp[i]   = hprev[i];
                hprev[i] = hv;
                hs[t & 1][q * 4 + i][jcol] = (_Float16)hv;
            }

            __syncthreads();   // single barrier per step
        }
    }

    // ---- epilogue ----
    // pending 1: beta_510 (in bcast[1], written at t=511) with hpp = h_510
    {
        f32x4 bb = *(const f32x4*)&bcast[1][q * 4];
#pragma unroll
        for (int i = 0; i < 4; ++i) P[i] = fmaf(bb[i], hpp[i], P[i]);
    }
    // pending 2: logit for h_511 (in hs[1])
    {
        half4 hh = *(const half4*)&hs[1][rrow][kc * 4];
        float acc = 0.f;
#pragma unroll
        for (int i = 0; i < 4; ++i) acc = fmaf(aw[i], (float)hh[i], acc);
#pragma unroll
        for (int off = 1; off < 32; off <<= 1) acc += __shfl_xor(acc, off, 64);
        float beta = __expf(acc + attb);
        Sreg += beta;
        if (kc == 0) { bcast[0][rrow] = beta; Sf[rrow] = Sreg; }
    }
    __syncthreads();
    float* sc = (float*)&hs[0][0][0];   // reuse as [16][132] fp32 scratch
#pragma unroll
    for (int i = 0; i < 4; ++i) {
        const int r_i = q * 4 + i;
        float Pv = fmaf(bcast[0][r_i], hprev[i], P[i]);
        sc[r_i * 132 + jcol] = (Pv / Sf[r_i]) * fcwj;
    }
    __syncthreads();
    {
        float acc2 = 0.f;
#pragma unroll
        for (int i = 0; i < 4; ++i) acc2 += sc[rrow * 132 + kc * 4 + i];
#pragma unroll
        for (int off = 1; off < 32; off <<= 1) acc2 += __shfl_xor(acc2, off, 64);
        if (kc == 0) out[b0 + rrow] = acc2 + fc_b[0];
    }
}

// ---------------------------------------------------------------------------
extern "C" void kernel_launch(void* const* d_in, const int* in_sizes, int n_in,
                              void* d_out, int out_size, void* d_ws, size_t ws_size,
                              hipStream_t stream) {
    const float* x      = (const float*)d_in[0];
    const float* w_ih   = (const float*)d_in[1];
    const float* u_ih   = (const float*)d_in[2];
    const float* w_hh   = (const float*)d_in[3];
    const float* u_hh   = (const float*)d_in[4];
    const float* b_ih   = (const float*)d_in[5];
    const float* b_hh   = (const float*)d_in[6];
    const float* attn_w = (const float*)d_in[7];
    const float* attn_b = (const float*)d_in[8];
    const float* fc_w   = (const float*)d_in[9];
    const float* u_fc   = (const float*)d_in[10];
    const float* fc_b   = (const float*)d_in[11];
    float* ws  = (float*)d_ws;
    float* out = (float*)d_out;

    std_kernel<<<TT, 256, 0, stream>>>(x, ws);
    sigma_kernel<<<1, 512, 0, stream>>>(w_ih, u_ih, w_hh, u_hh, fc_w, u_fc, ws);
    lstm_mfma<<<BB / 16, 512, 0, stream>>>(x, w_ih, w_hh, b_ih, b_hh,
                                           attn_w, attn_b, fc_w, fc_b, ws, out);
}

// Round 6
// 643.900 us; speedup vs baseline: 1.7907x; 1.7907x over previous
//
#include <hip/hip_runtime.h>
#include <math.h>

#define TT 512
#define BB 512
#define CC 32
#define CIN 33
#define HH 128
#define EPSF 1e-12f
#define CH 16              // timesteps per x-chunk staged in LDS
#define NCH (TT / CH)
#define RB 4               // batch rows per block

typedef _Float16 half8 __attribute__((ext_vector_type(8)));
typedef _Float16 half4v __attribute__((ext_vector_type(4)));
typedef _Float16 half2v __attribute__((ext_vector_type(2)));
typedef float f32x4 __attribute__((ext_vector_type(4)));

#define MFMA16H(a, b, c) __builtin_amdgcn_mfma_f32_16x16x32_f16(a, b, c, 0, 0, 0)

__device__ __forceinline__ float fsig(float x) {
    return __builtin_amdgcn_rcpf(1.f + __expf(-x));          // 2 trans, no div seq
}
__device__ __forceinline__ float ftanh(float x) {
    return 1.f - 2.f * __builtin_amdgcn_rcpf(1.f + __expf(2.f * x));
}

// ---------------------------------------------------------------------------
// Kernel 1: s[t] = mean_c std_b(x[:,t,c], ddof=1)   -> ws[0..511]
// ---------------------------------------------------------------------------
__global__ void std_kernel(const float* __restrict__ x, float* __restrict__ ws) {
    const int t = blockIdx.x;
    const int c = threadIdx.x & 31;
    const int sl = threadIdx.x >> 5;
    float sum = 0.f, sq = 0.f;
    for (int k = 0; k < 64; ++k) {
        const int b = sl * 64 + k;
        float v = x[((size_t)b * TT + t) * CC + c];
        sum += v;
        sq  = fmaf(v, v, sq);
    }
    __shared__ float rs[8][32];
    __shared__ float rq[8][32];
    rs[sl][c] = sum; rq[sl][c] = sq;
    __syncthreads();
    if (threadIdx.x < 32) {
        float S = 0.f, Q = 0.f;
        for (int i = 0; i < 8; ++i) { S += rs[i][threadIdx.x]; Q += rq[i][threadIdx.x]; }
        float mean = S / 512.0f;
        float var  = (Q - 512.0f * mean * mean) / 511.0f;
        rs[0][threadIdx.x] = sqrtf(fmaxf(var, 0.f));
    }
    __syncthreads();
    if (threadIdx.x == 0) {
        float m = 0.f;
        for (int i = 0; i < 32; ++i) m += rs[0][i];
        ws[t] = m / 32.0f;
    }
}

// ---------------------------------------------------------------------------
// Kernel 2: sigmas -> ws[512]=sig_ih, ws[513]=sig_hh, ws[514]=sig_fc
// ---------------------------------------------------------------------------
__global__ void sigma_kernel(const float* __restrict__ w_ih, const float* __restrict__ u_ih,
                             const float* __restrict__ w_hh, const float* __restrict__ u_hh,
                             const float* __restrict__ fc_w, const float* __restrict__ u_fc,
                             float* __restrict__ ws) {
    const int tid = threadIdx.x;
    __shared__ float red[512];
    __shared__ float vv[128];

    {   // sigma_hh
        const int c = tid & 127, q = tid >> 7;
        float part = 0.f;
        for (int g = q * 128; g < q * 128 + 128; ++g)
            part = fmaf(w_hh[g * HH + c], u_hh[g], part);
        red[tid] = part;
        __syncthreads();
        if (tid < 128) vv[tid] = red[tid] + red[tid + 128] + red[tid + 256] + red[tid + 384];
        __syncthreads();
        red[tid] = (tid < 128) ? vv[tid] * vv[tid] : 0.f;
        __syncthreads();
        for (int s = 64; s >= 1; s >>= 1) { if (tid < s) red[tid] += red[tid + s]; __syncthreads(); }
        const float nv = sqrtf(red[0]);
        __syncthreads();
        if (tid < 128) vv[tid] = vv[tid] / (nv + EPSF);
        __syncthreads();
        float wv = 0.f;
        for (int c2 = 0; c2 < 128; ++c2) wv = fmaf(w_hh[tid * HH + c2], vv[c2], wv);
        red[tid] = wv * wv;
        __syncthreads();
        for (int s = 256; s >= 1; s >>= 1) { if (tid < s) red[tid] += red[tid + s]; __syncthreads(); }
        if (tid == 0) { float ns2 = red[0]; ws[513] = ns2 / (sqrtf(ns2) + EPSF); }
        __syncthreads();
    }
    {   // sigma_ih
        float part = 0.f;
        if (tid < CIN) {
            for (int g = 0; g < 512; ++g) part = fmaf(w_ih[g * CIN + tid], u_ih[g], part);
            red[tid] = part;
        }
        __syncthreads();
        if (tid == 0) {
            float n2 = 0.f;
            for (int i = 0; i < CIN; ++i) n2 += red[i] * red[i];
            red[400] = sqrtf(n2);
        }
        __syncthreads();
        const float nv = red[400];
        if (tid < CIN) vv[tid] = red[tid] / (nv + EPSF);
        __syncthreads();
        float wv = 0.f;
        for (int c2 = 0; c2 < CIN; ++c2) wv = fmaf(w_ih[tid * CIN + c2], vv[c2], wv);
        red[tid] = wv * wv;
        __syncthreads();
        for (int s = 256; s >= 1; s >>= 1) { if (tid < s) red[tid] += red[tid + s]; __syncthreads(); }
        if (tid == 0) { float ns2 = red[0]; ws[512] = ns2 / (sqrtf(ns2) + EPSF); }
        __syncthreads();
    }
    {   // sigma_fc
        red[tid] = (tid < 128) ? fc_w[tid] * fc_w[tid] : 0.f;
        __syncthreads();
        for (int s = 64; s >= 1; s >>= 1) { if (tid < s) red[tid] += red[tid + s]; __syncthreads(); }
        if (tid == 0) {
            float nw2 = red[0];
            float u0  = u_fc[0];
            float nv  = fabsf(u0) * sqrtf(nw2);
            float wv  = u0 * nw2 / (nv + EPSF);
            ws[514]   = wv * wv / (fabsf(wv) + EPSF);
        }
    }
}

// ---------------------------------------------------------------------------
// Kernel 3: fp16 MFMA LSTM. 128 blocks x 4 batch rows, 512 threads (8 waves).
// Round-6: active-CU VALU was ~saturated by activations (divide sequences +
// 40 trans/thread). Now: 4 rows/block (4x less activation work per CU, 96
// more CUs active), gate compaction so every lane owns exactly ONE h-element
// (lane (q,c) -> row q, col 16w+c; 10 trans/thread/step), and rcpf instead
// of fp32 divides. MFMA per wave unchanged (N=512 gates needed regardless).
// ---------------------------------------------------------------------------
__global__ __attribute__((amdgpu_flat_work_group_size(512, 512), amdgpu_waves_per_eu(2, 2)))
void lstm_mfma(
    const float* __restrict__ x,
    const float* __restrict__ w_ih, const float* __restrict__ w_hh,
    const float* __restrict__ b_ih, const float* __restrict__ b_hh,
    const float* __restrict__ attn_w, const float* __restrict__ attn_b,
    const float* __restrict__ fc_w, const float* __restrict__ fc_b,
    const float* __restrict__ ws,
    float* __restrict__ out)
{
    const int tid = threadIdx.x;
    const int w   = tid >> 6;          // wave 0..7
    const int l   = tid & 63;          // lane
    const int m   = l & 15;            // A-row / B-col index
    const int q   = l >> 4;            // quad 0..3 == this lane's batch row
    const int b0  = blockIdx.x * RB;
    const int colg = 16 * w + m;       // this lane's h column

    const float rih = 1.f / ws[512];
    const float rhh = 1.f / ws[513];
    const float rfc = 1.f / ws[514];
    const float attb = attn_b[0];

    __shared__ __align__(16) _Float16 hs[2][16][136];        // rows 4..15 stay 0
    __shared__ __align__(16) _Float16 xs[2][CH][16][40];     // rows 4..15 stay 0
    __shared__ float ss[2][CH];
    __shared__ __align__(16) float gact[8][4][16][4];        // [wave][gate][col][row]
    __shared__ float bcast[2][RB];
    __shared__ float Sf[RB];
    __shared__ float sc[RB][132];

    // ---- stationary fp16 weights: B-frags Bf[p][kt] ----
    half8 Bf[4][5];
    float biasg[4], w32g[4];
#pragma unroll
    for (int p = 0; p < 4; ++p) {
        const int g = 16 * w + 128 * p + m;
#pragma unroll
        for (int kt = 0; kt < 4; ++kt) {
            const float* src = w_hh + (size_t)g * HH + kt * 32 + q * 8;
#pragma unroll
            for (int i = 0; i < 8; ++i) Bf[p][kt][i] = (_Float16)(src[i] * rhh);
        }
        {
            const float* src = w_ih + (size_t)g * CIN + q * 8;
#pragma unroll
            for (int i = 0; i < 8; ++i) Bf[p][4][i] = (_Float16)(src[i] * rih);
        }
        w32g[p]  = w_ih[(size_t)g * CIN + 32] * rih;
        biasg[p] = b_ih[g] + b_hh[g];
    }
#pragma unroll
    for (int p = 0; p < 4; ++p) {
#pragma unroll
        for (int kt = 0; kt < 5; ++kt) asm volatile("" : "+v"(Bf[p][kt]));
        asm volatile("" : "+v"(biasg[p]), "+v"(w32g[p]));
    }
    const float fcwj = fc_w[colg] * rfc;

    // logit-phase constants: wave r (<RB) handles batch row r; lane covers 2 cols
    const float aw0 = attn_w[2 * l];
    const float aw1 = attn_w[2 * l + 1];

    // zero hs (both buffers, all rows) and xs (both buffers, all rows)
    for (int i = tid; i < 2 * 16 * 136; i += 512) (&hs[0][0][0])[i] = (_Float16)0.f;
    for (int i = tid; i < 2 * CH * 16 * 40; i += 512) (&xs[0][0][0][0])[i] = (_Float16)0.f;
    __syncthreads();
    // stage chunk 0 (rows 0..3 only) + ss[0]
    {
        const int c4 = tid & 7, k = (tid >> 3) & 15, r = (tid >> 7) & 3;
        float4 xv = *reinterpret_cast<const float4*>(x + ((size_t)(b0 + r) * TT + k) * CC + c4 * 4);
        half4v hv = {(_Float16)xv.x, (_Float16)xv.y, (_Float16)xv.z, (_Float16)xv.w};
        *(half4v*)&xs[0][k][r][c4 * 4] = hv;
    }
    if (tid < CH) ss[0][tid] = ws[tid];

    float c_st = 0.f, P = 0.f, hprev = 0.f, hpp = 0.f;   // per-lane single element
    float Sreg = 0.f;
    __syncthreads();

    for (int tc = 0; tc < NCH; ++tc) {
        const int cb = tc & 1;

        // stage next chunk (drains at first in-chunk barrier)
        if (tc + 1 < NCH) {
            const int nb  = (tc + 1) & 1;
            const int t0n = (tc + 1) * CH;
            const int c4 = tid & 7, k = (tid >> 3) & 15, r = (tid >> 7) & 3;
            float4 xv = *reinterpret_cast<const float4*>(
                x + ((size_t)(b0 + r) * TT + (t0n + k)) * CC + c4 * 4);
            half4v hv = {(_Float16)xv.x, (_Float16)xv.y, (_Float16)xv.z, (_Float16)xv.w};
            *(half4v*)&xs[nb][k][r][c4 * 4] = hv;
            if (tid < CH) ss[nb][tid] = ws[t0n + tid];
        }

        for (int k = 0; k < CH; ++k) {
            const int t  = tc * CH + k;
            const int hb = (t + 1) & 1;    // buffer holding h_{t-1}

            // ---- A-frag LDS reads issued first ----
            half8 ah0 = *(const half8*)&hs[hb][m][0 * 32 + q * 8];
            half8 ah1 = *(const half8*)&hs[hb][m][1 * 32 + q * 8];
            half8 ah2 = *(const half8*)&hs[hb][m][2 * 32 + q * 8];
            half8 ah3 = *(const half8*)&hs[hb][m][3 * 32 + q * 8];
            half8 ah4 = *(const half8*)&xs[cb][k][m][q * 8];
            const float s_t = ss[cb][k];

            // ---- logit for h_{t-1}: wave r<RB handles row r ----
            if (t > 0 && w < RB) {
                half2v hh = *(const half2v*)&hs[hb][w][2 * l];
                float acc = fmaf(aw0, (float)hh[0], aw1 * (float)hh[1]);
#pragma unroll
                for (int off = 1; off < 64; off <<= 1) acc += __shfl_xor(acc, off, 64);
                float beta = __expf(acc + attb);
                Sreg += beta;
                if (l == 0) bcast[t & 1][w] = beta;
            }

            // ---- P update for h_{t-2} (beta written at step t-1) ----
            if (t >= 2) P = fmaf(bcast[(t - 1) & 1][q], hpp, P);

            // ---- gates: C init + 20 MFMA ----
            f32x4 acc0, acc1, acc2, acc3;
            {
                float c0 = fmaf(w32g[0], s_t, biasg[0]);
                float c1 = fmaf(w32g[1], s_t, biasg[1]);
                float c2 = fmaf(w32g[2], s_t, biasg[2]);
                float c3 = fmaf(w32g[3], s_t, biasg[3]);
                acc0 = (f32x4){c0, c0, c0, c0};
                acc1 = (f32x4){c1, c1, c1, c1};
                acc2 = (f32x4){c2, c2, c2, c2};
                acc3 = (f32x4){c3, c3, c3, c3};
            }
            acc0 = MFMA16H(ah0, Bf[0][0], acc0);
            acc1 = MFMA16H(ah0, Bf[1][0], acc1);
            acc2 = MFMA16H(ah0, Bf[2][0], acc2);
            acc3 = MFMA16H(ah0, Bf[3][0], acc3);
            acc0 = MFMA16H(ah1, Bf[0][1], acc0);
            acc1 = MFMA16H(ah1, Bf[1][1], acc1);
            acc2 = MFMA16H(ah1, Bf[2][1], acc2);
            acc3 = MFMA16H(ah1, Bf[3][1], acc3);
            acc0 = MFMA16H(ah2, Bf[0][2], acc0);
            acc1 = MFMA16H(ah2, Bf[1][2], acc1);
            acc2 = MFMA16H(ah2, Bf[2][2], acc2);
            acc3 = MFMA16H(ah2, Bf[3][2], acc3);
            acc0 = MFMA16H(ah3, Bf[0][3], acc0);
            acc1 = MFMA16H(ah3, Bf[1][3], acc1);
            acc2 = MFMA16H(ah3, Bf[2][3], acc2);
            acc3 = MFMA16H(ah3, Bf[3][3], acc3);
            acc0 = MFMA16H(ah4, Bf[0][4], acc0);
            acc1 = MFMA16H(ah4, Bf[1][4], acc1);
            acc2 = MFMA16H(ah4, Bf[2][4], acc2);
            acc3 = MFMA16H(ah4, Bf[3][4], acc3);

            // ---- gate compaction: q=0 lanes hold all real rows; spread 1/lane ----
            if (q == 0) {
                *(f32x4*)&gact[w][0][m][0] = acc0;
                *(f32x4*)&gact[w][1][m][0] = acc1;
                *(f32x4*)&gact[w][2][m][0] = acc2;
                *(f32x4*)&gact[w][3][m][0] = acc3;
            }
            float g0 = gact[w][0][m][q];   // intra-wave: lgkmcnt wait only, no barrier
            float g1 = gact[w][1][m][q];
            float g2 = gact[w][2][m][q];
            float g3 = gact[w][3][m][q];

            // ---- activation + state update: ONE element per lane ----
            {
                float ig = fsig(g0);
                float fg = fsig(g1);
                float gg = ftanh(g2);
                float og = fsig(g3);
                c_st = fmaf(fg, c_st, ig * gg);
                float hv = og * ftanh(c_st);
                hpp   = hprev;
                hprev = hv;
                hs[t & 1][q][colg] = (_Float16)hv;
            }

            __syncthreads();   // single barrier per step
        }
    }

    // ---- epilogue ----
    P = fmaf(bcast[1][q], hpp, P);            // beta_510 * h_510
    if (w < RB) {                              // beta_511 from hs[1]
        half2v hh = *(const half2v*)&hs[1][w][2 * l];
        float acc = fmaf(aw0, (float)hh[0], aw1 * (float)hh[1]);
#pragma unroll
        for (int off = 1; off < 64; off <<= 1) acc += __shfl_xor(acc, off, 64);
        float beta = __expf(acc + attb);
        Sreg += beta;
        if (l == 0) { bcast[0][w] = beta; Sf[w] = Sreg; }
    }
    __syncthreads();
    {
        float Pv = fmaf(bcast[0][q], hprev, P);
        sc[q][colg] = Pv * __builtin_amdgcn_rcpf(Sf[q]) * fcwj;
    }
    __syncthreads();
    if (w < RB) {
        float2 vv = *(const float2*)&sc[w][2 * l];
        float a = vv.x + vv.y;
#pragma unroll
        for (int off = 1; off < 64; off <<= 1) a += __shfl_xor(a, off, 64);
        if (l == 0) out[b0 + w] = a + fc_b[0];
    }
}

// ---------------------------------------------------------------------------
extern "C" void kernel_launch(void* const* d_in, const int* in_sizes, int n_in,
                              void* d_out, int out_size, void* d_ws, size_t ws_size,
                              hipStream_t stream) {
    const float* x      = (const float*)d_in[0];
    const float* w_ih   = (const float*)d_in[1];
    const float* u_ih   = (const float*)d_in[2];
    const float* w_hh   = (const float*)d_in[3];
    const float* u_hh   = (const float*)d_in[4];
    const float* b_ih   = (const float*)d_in[5];
    const float* b_hh   = (const float*)d_in[6];
    const float* attn_w = (const float*)d_in[7];
    const float* attn_b = (const float*)d_in[8];
    const float* fc_w   = (const float*)d_in[9];
    const float* u_fc   = (const float*)d_in[10];
    const float* fc_b   = (const float*)d_in[11];
    float* ws  = (float*)d_ws;
    float* out = (float*)d_out;

    std_kernel<<<TT, 256, 0, stream>>>(x, ws);
    sigma_kernel<<<1, 512, 0, stream>>>(w_ih, u_ih, w_hh, u_hh, fc_w, u_fc, ws);
    lstm_mfma<<<BB / RB, 512, 0, stream>>>(x, w_ih, w_hh, b_ih, b_hh,
                                           attn_w, attn_b, fc_w, fc_b, ws, out);
}